// Round 7
// baseline (2585.794 us; speedup 1.0000x reference)
//
#include <hip/hip_runtime.h>

#define CRF_B 512
#define CRF_T 2048
#define CRF_K 32
#define CRF_Q (CRF_T / 4)   // 512 packed-bp dwords per batch per column

// DPP ROW_NEWBCAST:k (CDNA, ctrl = 0x150+k): every lane of each 16-lane row
// reads that row's lane k. Pure VALU cross-lane -- no DS, no SGPR hazards.
// Slot layout: c[s] holds candidate (s ^ rsel) where rsel = 16 for odd rows.
template<int KK>
__device__ __forceinline__ void dpp_cands(int va, int vb, const float (&tr)[CRF_K],
                                          float (&c)[CRF_K]) {
    if constexpr (KK < 16) {
        c[KK] = __int_as_float(
            __builtin_amdgcn_update_dpp(0, va, 0x150 + KK, 0xf, 0xf, true)) + tr[KK];
        c[16 + KK] = __int_as_float(
            __builtin_amdgcn_update_dpp(0, vb, 0x150 + KK, 0xf, 0xf, true)) + tr[16 + KK];
        dpp_cands<KK + 1>(va, vb, tr, c);
    }
}

__global__ __launch_bounds__(64, 1) void crf_fused(
    const float* __restrict__ pot,    // [B,T,K]
    const float* __restrict__ trans,  // [K,K]
    float* __restrict__ out,          // [B,T,K] one-hot fp32
    unsigned int* __restrict__ bp)    // ws: [B, Q, K] packed backpointers
{
    const int b = blockIdx.x;
    const int l = threadIdx.x;
    const int j = l & 31;             // dest tag this lane carries (dup upper half)
    const int isr1 = (l >> 4) & 1;    // odd 16-row?
    const int rsel = isr1 << 4;       // slot->candidate index xor

    // tr[slot] = trans[slot ^ rsel][j]
    float tr[CRF_K];
#pragma unroll
    for (int s = 0; s < CRF_K; ++s) tr[s] = trans[(s ^ rsel) * CRF_K + j];

    const float* potb = pot + (size_t)b * (CRF_T * CRF_K);
    unsigned int* bpb = bp + (size_t)b * (CRF_Q * CRF_K);
    float* outb = out + (size_t)b * (CRF_T * CRF_K);

    // vA: lane l holds state[l&31]; vB: row-swapped copy state[(l&31)^16]
    float vA = potb[j];
    float vB = potb[j ^ 16];

    // potential double-buffer: cur = this group's pot rows, nxt = next group's
    float cur[4], nxt[4];
#pragma unroll
    for (int t = 1; t < 4; ++t) cur[t] = potb[t * CRF_K + j];

    for (int q = 0; q < CRF_Q; ++q) {
        // prefetch next group's potentials (issued early, consumed next q)
        {
            const int tb = (q + 1) * 4;
#pragma unroll
            for (int sx = 0; sx < 4; ++sx) {
                int t = tb + sx; if (t > CRF_T - 1) t = CRF_T - 1;
                nxt[sx] = potb[t * CRF_K + j];
            }
        }
        unsigned int bpack = 0;
#pragma unroll
        for (int sx = 0; sx < 4; ++sx) {
            if (q == 0 && sx == 0) continue;   // t=0 has no backpointer

            // ---- candidates via DPP row_newbcast (pure VALU) ----
            float c[CRF_K];
            dpp_cands<0>(__float_as_int(vA), __float_as_int(vB), tr, c);

            // ---- tournament (R2 semantics): value via v_max, index via
            // cmp+cndmask; right wins only if strictly greater (slots are
            // index-ascending within each 16-subtree for every row) ----
            float v16[16]; int x16[16];
#pragma unroll
            for (int k = 0; k < 16; ++k) {
                bool t = c[2 * k + 1] > c[2 * k];
                v16[k] = fmaxf(c[2 * k], c[2 * k + 1]);
                x16[k] = t ? (2 * k + 1) : (2 * k);
            }
            float v8[8]; int x8[8];
#pragma unroll
            for (int k = 0; k < 8; ++k) {
                bool t = v16[2 * k + 1] > v16[2 * k];
                v8[k] = fmaxf(v16[2 * k], v16[2 * k + 1]);
                x8[k] = t ? x16[2 * k + 1] : x16[2 * k];
            }
            float v4[4]; int x4[4];
#pragma unroll
            for (int k = 0; k < 4; ++k) {
                bool t = v8[2 * k + 1] > v8[2 * k];
                v4[k] = fmaxf(v8[2 * k], v8[2 * k + 1]);
                x4[k] = t ? x8[2 * k + 1] : x8[2 * k];
            }
            float v2[2]; int x2[2];
#pragma unroll
            for (int k = 0; k < 2; ++k) {
                bool t = v4[2 * k + 1] > v4[2 * k];
                v2[k] = fmaxf(v4[2 * k], v4[2 * k + 1]);
                x2[k] = t ? x4[2 * k + 1] : x4[2 * k];
            }
            // final merge: for odd rows the RIGHT subtree holds the lower
            // candidate indices (slots ^16), so right wins ties there
            bool gt = v2[1] > v2[0];
            bool eq = v2[1] == v2[0];
            bool tf = gt || (isr1 && eq);
            float m = fmaxf(v2[0], v2[1]);
            int mi = (tf ? x2[1] : x2[0]) ^ rsel;   // slot -> candidate index

            vA = m + cur[sx];
            // refresh row-swapped copy (single DS op; latency hides under the
            // vB-independent left half of next step's tournament)
            vB = __int_as_float(
                __builtin_amdgcn_ds_swizzle(__float_as_int(vA), 0x401F)); // lane^16
            bpack |= ((unsigned int)mi) << (8 * sx);
        }
        bpb[q * CRF_K + j] = bpack;    // halves store identical values (benign)
#pragma unroll
        for (int sx = 0; sx < 4; ++sx) cur[sx] = nxt[sx];
    }

    // ---------------- last tag (argmax over final state, first-index ties) ----
    __shared__ float fs[CRF_K];
    if (l < CRF_K) fs[l] = vA;        // lanes 0-31 hold state[j] at lane j
    __syncthreads();
    int bt = 0; float bv = fs[0];
#pragma unroll
    for (int jj = 1; jj < CRF_K; ++jj) {
        float v = fs[jj];
        if (v > bv) { bv = v; bt = jj; }
    }
    int stag = __builtin_amdgcn_readfirstlane(bt);

    const int cc = l & 31;
    // one-hot row for t = T-1 (halves write identical 128B row)
    outb[(CRF_T - 1) * CRF_K + cc] = (cc == stag) ? 1.0f : 0.0f;

    __threadfence();   // make own bp stores visible before read-back

    // ---------------- backtrack: lane cc holds COLUMN cc of bp ----------------
    for (int q0 = CRF_Q - 16; q0 >= 0; q0 -= 16) {
        unsigned int col[16];
#pragma unroll
        for (int r = 0; r < 16; ++r) col[r] = bpb[(q0 + r) * CRF_K + cc];
#pragma unroll
        for (int r = 15; r >= 0; --r) {
#pragma unroll
            for (int bi = 3; bi >= 0; --bi) {
                const int t = (q0 + r) * 4 + bi;
                if (t == 0) continue;   // only q0==0, r==0, bi==0
                unsigned int dw = (unsigned int)__builtin_amdgcn_readlane((int)col[r], stag);
                stag = (int)((dw >> (8 * bi)) & 255u);
                outb[(size_t)(t - 1) * CRF_K + cc] = (cc == stag) ? 1.0f : 0.0f;
            }
        }
    }
}

extern "C" void kernel_launch(void* const* d_in, const int* in_sizes, int n_in,
                              void* d_out, int out_size, void* d_ws, size_t ws_size,
                              hipStream_t stream) {
    const float* pot   = (const float*)d_in[0];   // inputs [512,2048,32] fp32
    const float* trans = (const float*)d_in[1];   // transitions [32,32] fp32
    float* out = (float*)d_out;
    unsigned int* bp = (unsigned int*)d_ws;       // needs 33,554,432 B

    crf_fused<<<dim3(CRF_B), dim3(64), 0, stream>>>(pot, trans, out, bp);
}